// Round 5
// baseline (199.718 us; speedup 1.0000x reference)
//
#include <hip/hip_runtime.h>

#define D 128

typedef __attribute__((ext_vector_type(8))) short short8;
typedef __attribute__((ext_vector_type(4))) float f32x4;

typedef __attribute__((address_space(3))) unsigned int lds_u32_t;
typedef const __attribute__((address_space(1))) unsigned int glb_u32_t;

static __device__ __forceinline__ unsigned short f2bf(float f) {
    unsigned int u = __float_as_uint(f);
    unsigned int r = (u + 0x7fffu + ((u >> 16) & 1u)) >> 16;
    return (unsigned short)r;
}
static __device__ __forceinline__ float bf_lo(unsigned int u) {
    return __uint_as_float(u << 16);
}
static __device__ __forceinline__ float bf_hi(unsigned int u) {
    return __uint_as_float(u & 0xffff0000u);
}
static __device__ __forceinline__ unsigned int pack2(float lo, float hi) {
    return (unsigned int)f2bf(lo) | ((unsigned int)f2bf(hi) << 16);
}
static __device__ __forceinline__ void acc8(float* acc, uint4 v) {
    acc[0] += bf_lo(v.x); acc[1] += bf_hi(v.x);
    acc[2] += bf_lo(v.y); acc[3] += bf_hi(v.y);
    acc[4] += bf_lo(v.z); acc[5] += bf_hi(v.z);
    acc[6] += bf_lo(v.w); acc[7] += bf_hi(v.w);
}

// ---------------- prep: convert W (blocks 0..31), convert x + zero cnt (rest) ----------------

__global__ void prep_kernel(const float* __restrict__ x, unsigned short* __restrict__ xb,
                            int total8,
                            const float* __restrict__ W0, const float* __restrict__ W1,
                            const float* __restrict__ W2, const float* __restrict__ W3,
                            unsigned short* __restrict__ wt,
                            int* __restrict__ cnt, int N) {
    int bx = blockIdx.x;
    int t = threadIdx.x;
    if (bx < 32) {
        // W [128k][128n] fp32 -> wt bf16 [m][n][chunk-swizzled k]: chunk c at slot c ^ (n&15)
        int tid = bx * 256 + t;            // 0..8191
        int m = tid >> 11;
        const float* W = (m == 0) ? W0 : (m == 1) ? W1 : (m == 2) ? W2 : W3;
        int r = tid & 2047;
        int n = r >> 4;
        int c = r & 15;
        float f[8];
#pragma unroll
        for (int i = 0; i < 8; ++i) f[i] = W[(size_t)(c * 8 + i) * 128 + n];
        uint4 o;
        o.x = pack2(f[0], f[1]);
        o.y = pack2(f[2], f[3]);
        o.z = pack2(f[4], f[5]);
        o.w = pack2(f[6], f[7]);
        *reinterpret_cast<uint4*>(wt + (size_t)m * 16384 + n * 128 + (c ^ (n & 15)) * 8) = o;
    } else {
        int i = (bx - 32) * 256 + t;
        if (i < N) cnt[i] = 0;
        if (i < total8) {
            const float4 v0 = *reinterpret_cast<const float4*>(x + (size_t)i * 8);
            const float4 v1 = *reinterpret_cast<const float4*>(x + (size_t)i * 8 + 4);
            uint4 o;
            o.x = pack2(v0.x, v0.y);
            o.y = pack2(v0.z, v0.w);
            o.z = pack2(v1.x, v1.y);
            o.w = pack2(v1.z, v1.w);
            *reinterpret_cast<uint4*>(xb + (size_t)i * 8) = o;
        }
    }
}

// ---------------- CSR build ----------------

__global__ void count_deg_kernel(const int* __restrict__ dst, int* __restrict__ cnt, int E) {
    int e = blockIdx.x * 256 + threadIdx.x;
    if (e < E) atomicAdd(&cnt[dst[e]], 1);
}

__global__ void scan1_kernel(const int* __restrict__ cnt, int* __restrict__ rowptr,
                             int* __restrict__ bsum, int N) {
    __shared__ int tmp[256];
    int tid = threadIdx.x;
    int i = blockIdx.x * 256 + tid;
    int v = (i < N) ? cnt[i] : 0;
    tmp[tid] = v;
    __syncthreads();
    for (int off = 1; off < 256; off <<= 1) {
        int t = (tid >= off) ? tmp[tid - off] : 0;
        __syncthreads();
        tmp[tid] += t;
        __syncthreads();
    }
    if (i < N) rowptr[i] = tmp[tid] - v;
    if (tid == 255) bsum[blockIdx.x] = tmp[255];
}

__global__ void scan2_kernel(int* __restrict__ bsum, int NB) {
    __shared__ int tmp[256];
    int tid = threadIdx.x;
    int v = (tid < NB) ? bsum[tid] : 0;
    tmp[tid] = v;
    __syncthreads();
    for (int off = 1; off < 256; off <<= 1) {
        int t = (tid >= off) ? tmp[tid - off] : 0;
        __syncthreads();
        tmp[tid] += t;
        __syncthreads();
    }
    if (tid < NB) bsum[tid] = tmp[tid] - v;
}

__global__ void scan3_kernel(int* __restrict__ rowptr, const int* __restrict__ bsum,
                             int* __restrict__ cursor, int N, int E) {
    int i = blockIdx.x * 256 + threadIdx.x;
    if (i < N) {
        int v = rowptr[i] + bsum[blockIdx.x];
        rowptr[i] = v;
        cursor[i] = v;
    }
    if (i == 0) rowptr[N] = E;
}

__global__ void fill_kernel(const int* __restrict__ src, const int* __restrict__ dst,
                            int* __restrict__ cursor, int* __restrict__ ssrc, int E) {
    int e = blockIdx.x * 256 + threadIdx.x;
    if (e < E) {
        int d = dst[e];
        int pos = atomicAdd(&cursor[d], 1);
        ssrc[pos] = src[e];
    }
}

// ---------------- fused SAGE layer: out = mean_agg(feat) @ W_l + feat @ W_r + b ----------------
// block: 256 thr / 4 waves; tile 64 rows x 128 cols; wave = 16 rows x 128 cols (N_rep=8).
// Phase A: gather-aggregate the block's 64 rows into Agg LDS (bf16, slot c^(r&15) swizzle),
//          overlapped with W_l global_load_lds.
// Phase B: pass 0 MFMA (A = Agg LDS), reload W_r, pass 1 MFMA (A = feat rows direct global).

template <bool RELU, bool OUT_BF16>
__global__ __launch_bounds__(256)
void sage_layer_kernel(const unsigned short* __restrict__ feat,   // [N_pad][128] bf16
                       const int* __restrict__ rowptr, const int* __restrict__ ssrc,
                       const unsigned short* __restrict__ Wt,     // [2][128n][128k-swz] bf16
                       const float* __restrict__ bias, void* __restrict__ outp, int N) {
    __shared__ unsigned short Wlds[128 * 128];   // 32 KB (swizzle baked in global layout)
    __shared__ unsigned short Agg[64 * 128];     // 16 KB: row r, chunk c at slot c^(r&15)

    const int t = threadIdx.x;
    const int w = t >> 6;
    const int lane = t & 63;
    const int l15 = lane & 15;
    const int g = lane >> 4;
    const size_t row0 = (size_t)blockIdx.x * 64;

    // ---- issue W_l load (pass-0 weights) ----
#pragma unroll
    for (int i = 0; i < 8; ++i) {
        int d = t + 256 * i;
        __builtin_amdgcn_global_load_lds((glb_u32_t*)(Wt + (size_t)d * 8),
                                         (lds_u32_t*)(&Wlds[d * 8]), 16, 0, 0);
    }

    // ---- gather-aggregate: quarter-wave (w*4+g) owns rows (w*4+g)*4 .. +3 ----
    {
        int qw = w * 4 + g;
#pragma unroll
        for (int rr = 0; rr < 4; ++rr) {
            int rt = qw * 4 + rr;                 // 0..63; rt & 15 == g*4+rr
            size_t grow = row0 + rt;
            float a[8] = {0.f, 0.f, 0.f, 0.f, 0.f, 0.f, 0.f, 0.f};
            int deg = 0;
            if (grow < (size_t)N) {
                int beg = rowptr[grow], end = rowptr[grow + 1];
                deg = end - beg;
                int e = beg;
                for (; e + 2 <= end; e += 2) {
                    int s0 = ssrc[e], s1 = ssrc[e + 1];
                    uint4 v0 = *reinterpret_cast<const uint4*>(feat + (size_t)s0 * D + l15 * 8);
                    uint4 v1 = *reinterpret_cast<const uint4*>(feat + (size_t)s1 * D + l15 * 8);
                    acc8(a, v0);
                    acc8(a, v1);
                }
                if (e < end) {
                    int s0 = ssrc[e];
                    uint4 v0 = *reinterpret_cast<const uint4*>(feat + (size_t)s0 * D + l15 * 8);
                    acc8(a, v0);
                }
            }
            float inv = 1.0f / (float)(deg > 1 ? deg : 1);
            uint4 o;
            o.x = pack2(a[0] * inv, a[1] * inv);
            o.y = pack2(a[2] * inv, a[3] * inv);
            o.z = pack2(a[4] * inv, a[5] * inv);
            o.w = pack2(a[6] * inv, a[7] * inv);
            *reinterpret_cast<uint4*>(&Agg[rt * D + (l15 ^ (rt & 15)) * 8]) = o;
        }
    }

    f32x4 acc[8];
#pragma unroll
    for (int j = 0; j < 8; ++j) acc[j] = (f32x4){0.f, 0.f, 0.f, 0.f};
    float bb[8];
#pragma unroll
    for (int j = 0; j < 8; ++j) bb[j] = bias[j * 16 + l15];

    __syncthreads();   // W_l in LDS (vmcnt drained), Agg writes visible

    // ---- pass 0: agg @ W_l (A from Agg LDS) ----
#pragma unroll
    for (int kiter = 0; kiter < 4; ++kiter) {
        int r0 = w * 16 + l15;
        int c = kiter * 4 + g;
        short8 a = *reinterpret_cast<const short8*>(&Agg[r0 * D + (c ^ l15) * 8]);
#pragma unroll
        for (int j = 0; j < 8; ++j) {
            short8 b = *reinterpret_cast<const short8*>(&Wlds[(j * 16 + l15) * 128 + (c ^ l15) * 8]);
            acc[j] = __builtin_amdgcn_mfma_f32_16x16x32_bf16(a, b, acc[j], 0, 0, 0);
        }
    }

    __syncthreads();   // all waves done reading W_l

    // ---- issue W_r load (pass-1 weights) ----
#pragma unroll
    for (int i = 0; i < 8; ++i) {
        int d = t + 256 * i;
        __builtin_amdgcn_global_load_lds((glb_u32_t*)(Wt + 16384 + (size_t)d * 8),
                                         (lds_u32_t*)(&Wlds[d * 8]), 16, 0, 0);
    }
    __syncthreads();   // W_r ready

    // ---- pass 1: feat @ W_r (A direct from global; g-lanes cover a 64B line per row) ----
#pragma unroll
    for (int kiter = 0; kiter < 4; ++kiter) {
        int c = kiter * 4 + g;
        short8 a = *reinterpret_cast<const short8*>(feat + (row0 + w * 16 + l15) * D + c * 8);
#pragma unroll
        for (int j = 0; j < 8; ++j) {
            short8 b = *reinterpret_cast<const short8*>(&Wlds[(j * 16 + l15) * 128 + (c ^ l15) * 8]);
            acc[j] = __builtin_amdgcn_mfma_f32_16x16x32_bf16(a, b, acc[j], 0, 0, 0);
        }
    }

    // ---- epilogue: C/D layout col=lane&15, row=(lane>>4)*4+reg ----
    unsigned short* outb = (unsigned short*)outp;
    float* outf = (float*)outp;
    size_t rbase = row0 + w * 16 + g * 4;
#pragma unroll
    for (int reg = 0; reg < 4; ++reg) {
        size_t row = rbase + reg;
        if (row < (size_t)N) {
#pragma unroll
            for (int j = 0; j < 8; ++j) {
                float v = acc[j][reg] + bb[j];
                if (RELU) v = v > 0.f ? v : 0.f;
                if (OUT_BF16) outb[row * D + j * 16 + l15] = f2bf(v);
                else          outf[row * D + j * 16 + l15] = v;
            }
        }
    }
}

// ---------------- launch ----------------

extern "C" void kernel_launch(void* const* d_in, const int* in_sizes, int n_in,
                              void* d_out, int out_size, void* d_ws, size_t ws_size,
                              hipStream_t stream) {
    const float* x    = (const float*)d_in[0];
    const int*   eidx = (const int*)d_in[1];
    const float* W_l1 = (const float*)d_in[2];
    const float* W_r1 = (const float*)d_in[3];
    const float* b1   = (const float*)d_in[4];
    const float* W_l2 = (const float*)d_in[5];
    const float* W_r2 = (const float*)d_in[6];
    const float* b2   = (const float*)d_in[7];
    float* out = (float*)d_out;

    const int N = in_sizes[0] / D;
    const int E = in_sizes[1] / 2;
    const int N_pad = (N + 127) & ~127;
    const int N_pad64 = (N + 63) & ~63;
    const int* src = eidx;
    const int* dst = eidx + E;

    char* ws = (char*)d_ws;
    size_t off = 0;
    auto alloc = [&](size_t bytes) {
        char* p = ws + off;
        off += (bytes + 511) & ~(size_t)511;
        return p;
    };
    int*            cnt    = (int*)alloc((size_t)N * 4);
    int*            rowptr = (int*)alloc((size_t)(N + 1) * 4);
    int*            cursor = (int*)alloc((size_t)N * 4);
    int*            bsum   = (int*)alloc(1024);
    int*            ssrc   = (int*)alloc((size_t)E * 4);
    unsigned short* xb     = (unsigned short*)alloc((size_t)N_pad * D * 2);
    unsigned short* hb     = (unsigned short*)alloc((size_t)N_pad * D * 2);
    unsigned short* wt     = (unsigned short*)alloc((size_t)4 * 128 * 128 * 2);

    const int total8   = N * D / 8;
    const int NB_prep  = 32 + (total8 + 255) / 256;
    const int NB_edges = (E + 255) / 256;
    const int NB_nodes = (N + 255) / 256;   // 196 <= 256, fits scan2's single block
    const int NB_gemm  = N_pad64 / 64;

    // prep (convert x/W, zero cnt) + CSR build
    prep_kernel<<<NB_prep, 256, 0, stream>>>(x, xb, total8, W_l1, W_r1, W_l2, W_r2, wt, cnt, N);
    count_deg_kernel<<<NB_edges, 256, 0, stream>>>(dst, cnt, E);
    scan1_kernel<<<NB_nodes, 256, 0, stream>>>(cnt, rowptr, bsum, N);
    scan2_kernel<<<1, 256, 0, stream>>>(bsum, NB_nodes);
    scan3_kernel<<<NB_nodes, 256, 0, stream>>>(rowptr, bsum, cursor, N, E);
    fill_kernel<<<NB_edges, 256, 0, stream>>>(src, dst, cursor, ssrc, E);

    // layer 1: h = relu(agg(x) @ W_l1 + x @ W_r1 + b1)
    sage_layer_kernel<true, true><<<NB_gemm, 256, 0, stream>>>(xb, rowptr, ssrc, wt, b1, hb, N);
    // layer 2: out = agg(h) @ W_l2 + h @ W_r2 + b2
    sage_layer_kernel<false, false><<<NB_gemm, 256, 0, stream>>>(hb, rowptr, ssrc, wt + 2 * 16384, b2, out, N);
}

// Round 6
// 156.722 us; speedup vs baseline: 1.2743x; 1.2743x over previous
//
#include <hip/hip_runtime.h>

#define D 128

typedef __attribute__((ext_vector_type(8))) short short8;
typedef __attribute__((ext_vector_type(4))) float f32x4;

typedef __attribute__((address_space(3))) unsigned int lds_u32_t;
typedef const __attribute__((address_space(1))) unsigned int glb_u32_t;

static __device__ __forceinline__ unsigned short f2bf(float f) {
    unsigned int u = __float_as_uint(f);
    unsigned int r = (u + 0x7fffu + ((u >> 16) & 1u)) >> 16;
    return (unsigned short)r;
}
static __device__ __forceinline__ float bf_lo(unsigned int u) {
    return __uint_as_float(u << 16);
}
static __device__ __forceinline__ float bf_hi(unsigned int u) {
    return __uint_as_float(u & 0xffff0000u);
}
static __device__ __forceinline__ unsigned int pack2(float lo, float hi) {
    return (unsigned int)f2bf(lo) | ((unsigned int)f2bf(hi) << 16);
}

// ------- prep: W convert (blocks 0..31), x convert (next xb_blocks), count_deg (rest) -------
// cnt must be zeroed (hipMemsetAsync) before this kernel runs.

__global__ void prep_kernel(const float* __restrict__ x, unsigned short* __restrict__ xb,
                            int total8, int xb_blocks,
                            const float* __restrict__ W0, const float* __restrict__ W1,
                            const float* __restrict__ W2, const float* __restrict__ W3,
                            unsigned short* __restrict__ wt,
                            const int* __restrict__ dst, int* __restrict__ cnt, int E) {
    int bx = blockIdx.x;
    int t = threadIdx.x;
    if (bx < 32) {
        // W [128k][128n] fp32 -> wt bf16 [m][n][chunk-swizzled k]: chunk c at slot c ^ (n&15)
        int tid = bx * 256 + t;            // 0..8191
        int m = tid >> 11;
        const float* W = (m == 0) ? W0 : (m == 1) ? W1 : (m == 2) ? W2 : W3;
        int r = tid & 2047;
        int n = r >> 4;
        int c = r & 15;
        float f[8];
#pragma unroll
        for (int i = 0; i < 8; ++i) f[i] = W[(size_t)(c * 8 + i) * 128 + n];
        uint4 o;
        o.x = pack2(f[0], f[1]);
        o.y = pack2(f[2], f[3]);
        o.z = pack2(f[4], f[5]);
        o.w = pack2(f[6], f[7]);
        *reinterpret_cast<uint4*>(wt + (size_t)m * 16384 + n * 128 + (c ^ (n & 15)) * 8) = o;
    } else if (bx < 32 + xb_blocks) {
        int i = (bx - 32) * 256 + t;
        if (i < total8) {
            const float4 v0 = *reinterpret_cast<const float4*>(x + (size_t)i * 8);
            const float4 v1 = *reinterpret_cast<const float4*>(x + (size_t)i * 8 + 4);
            uint4 o;
            o.x = pack2(v0.x, v0.y);
            o.y = pack2(v0.z, v0.w);
            o.z = pack2(v1.x, v1.y);
            o.w = pack2(v1.z, v1.w);
            *reinterpret_cast<uint4*>(xb + (size_t)i * 8) = o;
        }
    } else {
        int e = (bx - 32 - xb_blocks) * 256 + t;
        if (e < E) atomicAdd(&cnt[dst[e]], 1);
    }
}

// ---------------- CSR build ----------------

__global__ void scan1_kernel(const int* __restrict__ cnt, int* __restrict__ rowptr,
                             int* __restrict__ bsum, int N) {
    __shared__ int tmp[256];
    int tid = threadIdx.x;
    int i = blockIdx.x * 256 + tid;
    int v = (i < N) ? cnt[i] : 0;
    tmp[tid] = v;
    __syncthreads();
    for (int off = 1; off < 256; off <<= 1) {
        int t = (tid >= off) ? tmp[tid - off] : 0;
        __syncthreads();
        tmp[tid] += t;
        __syncthreads();
    }
    if (i < N) rowptr[i] = tmp[tid] - v;
    if (tid == 255) bsum[blockIdx.x] = tmp[255];
}

__global__ void scan2_kernel(int* __restrict__ bsum, int NB) {
    __shared__ int tmp[256];
    int tid = threadIdx.x;
    int v = (tid < NB) ? bsum[tid] : 0;
    tmp[tid] = v;
    __syncthreads();
    for (int off = 1; off < 256; off <<= 1) {
        int t = (tid >= off) ? tmp[tid - off] : 0;
        __syncthreads();
        tmp[tid] += t;
        __syncthreads();
    }
    if (tid < NB) bsum[tid] = tmp[tid] - v;
}

__global__ void scan3_kernel(int* __restrict__ rowptr, const int* __restrict__ bsum,
                             int* __restrict__ cursor, int N, int E) {
    int i = blockIdx.x * 256 + threadIdx.x;
    if (i < N) {
        int v = rowptr[i] + bsum[blockIdx.x];
        rowptr[i] = v;
        cursor[i] = v;
    }
    if (i == 0) rowptr[N] = E;
}

__global__ void fill_kernel(const int* __restrict__ src, const int* __restrict__ dst,
                            int* __restrict__ cursor, int* __restrict__ ssrc, int E) {
    int e = blockIdx.x * 256 + threadIdx.x;
    if (e < E) {
        int d = dst[e];
        int pos = atomicAdd(&cursor[d], 1);
        ssrc[pos] = src[e];
    }
}

// ---------------- mean aggregation (bf16 in, bf16 out, fp32 accum) ----------------
// one wave per node; quarter-waves process 4 edges concurrently; 16 lanes cover 128 elems

__global__ void agg_kernel(const unsigned short* __restrict__ feat, const int* __restrict__ rowptr,
                           const int* __restrict__ ssrc, unsigned short* __restrict__ out, int N) {
    int w = (blockIdx.x * blockDim.x + threadIdx.x) >> 6;
    if (w >= N) return;
    int lane = threadIdx.x & 63;
    int q = lane >> 4;
    int l15 = lane & 15;
    int beg = rowptr[w], end = rowptr[w + 1];
    float acc[8] = {0.f, 0.f, 0.f, 0.f, 0.f, 0.f, 0.f, 0.f};
    for (int e = beg + q; e < end; e += 4) {
        int s = ssrc[e];
        uint4 v = *reinterpret_cast<const uint4*>(feat + (size_t)s * D + l15 * 8);
        acc[0] += bf_lo(v.x); acc[1] += bf_hi(v.x);
        acc[2] += bf_lo(v.y); acc[3] += bf_hi(v.y);
        acc[4] += bf_lo(v.z); acc[5] += bf_hi(v.z);
        acc[6] += bf_lo(v.w); acc[7] += bf_hi(v.w);
    }
#pragma unroll
    for (int j = 0; j < 8; ++j) {
        acc[j] += __shfl_xor(acc[j], 16);
        acc[j] += __shfl_xor(acc[j], 32);
    }
    if (lane < 16) {
        int deg = end - beg;
        float inv = 1.0f / (float)(deg > 1 ? deg : 1);
        uint4 o;
        o.x = pack2(acc[0] * inv, acc[1] * inv);
        o.y = pack2(acc[2] * inv, acc[3] * inv);
        o.z = pack2(acc[4] * inv, acc[5] * inv);
        o.w = pack2(acc[6] * inv, acc[7] * inv);
        *reinterpret_cast<uint4*>(out + (size_t)w * D + l15 * 8) = o;
    }
}

// ---------------- MFMA dual-GEMM: out = A1*Wt[0] + A2*Wt[1] + bias [, relu] ----------------
// block: 256 thr / 4 waves; tile 128 rows x 128 cols; wave = 32 rows (M_rep=2) x 128 cols (N_rep=8).
// No A staging: A fragments preloaded direct from global (each A row consumed by exactly one
// block, so LDS A-staging had zero reuse). Both W passes resident in 64 KB LDS. ONE barrier.

template <bool RELU, bool OUT_BF16>
__global__ __launch_bounds__(256)
void gemm_mfma_kernel(const unsigned short* __restrict__ A1, const unsigned short* __restrict__ A2,
                      const unsigned short* __restrict__ Wt,   // [2][128n][128k-swz] bf16
                      const float* __restrict__ bias, void* __restrict__ outp, int N) {
    __shared__ unsigned short Wlds[2][128 * 128];   // 64 KB, swizzle baked in global layout

    const int t = threadIdx.x;
    const int w = t >> 6;
    const int lane = t & 63;
    const int l15 = lane & 15;
    const int g = lane >> 4;
    const size_t row0 = (size_t)blockIdx.x * 128;

    // issue both W loads (65536 B = 256 thr x 16 iters x 16 B)
#pragma unroll
    for (int i = 0; i < 16; ++i) {
        int d = t + 256 * i;    // short8 index 0..4095
        __builtin_amdgcn_global_load_lds((glb_u32_t*)(Wt + (size_t)d * 8),
                                         (lds_u32_t*)(&Wlds[0][0] + (size_t)d * 8), 16, 0, 0);
    }

    // preload all A fragments direct from global (rows >= N read junk; their outputs are dropped)
    short8 a[2][2][4];   // [pass][row-group][kiter]
#pragma unroll
    for (int p = 0; p < 2; ++p) {
        const unsigned short* __restrict__ Ap = p ? A2 : A1;
#pragma unroll
        for (int m = 0; m < 2; ++m) {
            size_t r = row0 + w * 32 + m * 16 + l15;
#pragma unroll
            for (int k = 0; k < 4; ++k)
                a[p][m][k] = *reinterpret_cast<const short8*>(Ap + r * D + (k * 4 + g) * 8);
        }
    }

    float bb[8];
#pragma unroll
    for (int j = 0; j < 8; ++j) bb[j] = bias[j * 16 + l15];

    f32x4 acc[2][8];
#pragma unroll
    for (int m = 0; m < 2; ++m)
#pragma unroll
        for (int j = 0; j < 8; ++j) acc[m][j] = (f32x4){0.f, 0.f, 0.f, 0.f};

    __syncthreads();   // drains vmcnt: W in LDS, A in regs

#pragma unroll
    for (int p = 0; p < 2; ++p)
#pragma unroll
        for (int k = 0; k < 4; ++k) {
            int c = k * 4 + g;
#pragma unroll
            for (int j = 0; j < 8; ++j) {
                short8 b = *reinterpret_cast<const short8*>(
                    &Wlds[p][(j * 16 + l15) * 128 + ((c ^ l15) * 8)]);
                acc[0][j] = __builtin_amdgcn_mfma_f32_16x16x32_bf16(a[p][0][k], b, acc[0][j], 0, 0, 0);
                acc[1][j] = __builtin_amdgcn_mfma_f32_16x16x32_bf16(a[p][1][k], b, acc[1][j], 0, 0, 0);
            }
        }

    // epilogue: C/D layout col=lane&15, row=(lane>>4)*4+reg
    unsigned short* outb = (unsigned short*)outp;
    float* outf = (float*)outp;
#pragma unroll
    for (int m = 0; m < 2; ++m) {
        size_t rbase = row0 + w * 32 + m * 16 + g * 4;
#pragma unroll
        for (int reg = 0; reg < 4; ++reg) {
            size_t row = rbase + reg;
            if (row < (size_t)N) {
#pragma unroll
                for (int j = 0; j < 8; ++j) {
                    float v = acc[m][j][reg] + bb[j];
                    if (RELU) v = v > 0.f ? v : 0.f;
                    if (OUT_BF16) outb[row * D + j * 16 + l15] = f2bf(v);
                    else          outf[row * D + j * 16 + l15] = v;
                }
            }
        }
    }
}

// ---------------- launch ----------------

extern "C" void kernel_launch(void* const* d_in, const int* in_sizes, int n_in,
                              void* d_out, int out_size, void* d_ws, size_t ws_size,
                              hipStream_t stream) {
    const float* x    = (const float*)d_in[0];
    const int*   eidx = (const int*)d_in[1];
    const float* W_l1 = (const float*)d_in[2];
    const float* W_r1 = (const float*)d_in[3];
    const float* b1   = (const float*)d_in[4];
    const float* W_l2 = (const float*)d_in[5];
    const float* W_r2 = (const float*)d_in[6];
    const float* b2   = (const float*)d_in[7];
    float* out = (float*)d_out;

    const int N = in_sizes[0] / D;
    const int E = in_sizes[1] / 2;
    const int N_pad = (N + 127) & ~127;
    const int* src = eidx;
    const int* dst = eidx + E;

    char* ws = (char*)d_ws;
    size_t off = 0;
    auto alloc = [&](size_t bytes) {
        char* p = ws + off;
        off += (bytes + 511) & ~(size_t)511;
        return p;
    };
    int*            cnt    = (int*)alloc((size_t)N * 4);
    int*            rowptr = (int*)alloc((size_t)(N + 1) * 4);
    int*            cursor = (int*)alloc((size_t)N * 4);
    int*            bsum   = (int*)alloc(1024);
    int*            ssrc   = (int*)alloc((size_t)E * 4);
    unsigned short* xb     = (unsigned short*)alloc((size_t)N_pad * D * 2);
    unsigned short* hb     = (unsigned short*)alloc((size_t)N_pad * D * 2);
    unsigned short* aggb   = (unsigned short*)alloc((size_t)N_pad * D * 2);
    unsigned short* wt     = (unsigned short*)alloc((size_t)4 * 128 * 128 * 2);

    const int total8    = N * D / 8;
    const int xb_blocks = (total8 + 255) / 256;
    const int NB_edges  = (E + 255) / 256;
    const int NB_prep   = 32 + xb_blocks + NB_edges;
    const int NB_nodes  = (N + 255) / 256;   // 196 <= 256, fits scan2's single block
    const int NB_agg    = (N + 3) / 4;
    const int NB_gemm   = N_pad / 128;

    // CSR + conversions
    hipMemsetAsync(cnt, 0, (size_t)N * 4, stream);
    prep_kernel<<<NB_prep, 256, 0, stream>>>(x, xb, total8, xb_blocks,
                                             W_l1, W_r1, W_l2, W_r2, wt, dst, cnt, E);
    scan1_kernel<<<NB_nodes, 256, 0, stream>>>(cnt, rowptr, bsum, N);
    scan2_kernel<<<1, 256, 0, stream>>>(bsum, NB_nodes);
    scan3_kernel<<<NB_nodes, 256, 0, stream>>>(rowptr, bsum, cursor, N, E);
    fill_kernel<<<NB_edges, 256, 0, stream>>>(src, dst, cursor, ssrc, E);

    // layer 1
    agg_kernel<<<NB_agg, 256, 0, stream>>>(xb, rowptr, ssrc, aggb, N);
    gemm_mfma_kernel<true, true><<<NB_gemm, 256, 0, stream>>>(aggb, xb, wt, b1, hb, N);

    // layer 2
    agg_kernel<<<NB_agg, 256, 0, stream>>>(hb, rowptr, ssrc, aggb, N);
    gemm_mfma_kernel<false, false><<<NB_gemm, 256, 0, stream>>>(aggb, hb, wt + 2 * 16384, b2, out, N);
}

// Round 8
// 148.786 us; speedup vs baseline: 1.3423x; 1.0533x over previous
//
#include <hip/hip_runtime.h>

#define D 128

typedef __attribute__((ext_vector_type(8))) short short8;
typedef __attribute__((ext_vector_type(4))) float f32x4;

typedef __attribute__((address_space(3))) unsigned int lds_u32_t;
typedef const __attribute__((address_space(1))) unsigned int glb_u32_t;

static __device__ __forceinline__ unsigned short f2bf(float f) {
    unsigned int u = __float_as_uint(f);
    unsigned int r = (u + 0x7fffu + ((u >> 16) & 1u)) >> 16;
    return (unsigned short)r;
}
static __device__ __forceinline__ float bf_lo(unsigned int u) {
    return __uint_as_float(u << 16);
}
static __device__ __forceinline__ float bf_hi(unsigned int u) {
    return __uint_as_float(u & 0xffff0000u);
}
static __device__ __forceinline__ unsigned int pack2(float lo, float hi) {
    return (unsigned int)f2bf(lo) | ((unsigned int)f2bf(hi) << 16);
}
static __device__ __forceinline__ void acc8(float* acc, uint4 v) {
    acc[0] += bf_lo(v.x); acc[1] += bf_hi(v.x);
    acc[2] += bf_lo(v.y); acc[3] += bf_hi(v.y);
    acc[4] += bf_lo(v.z); acc[5] += bf_hi(v.z);
    acc[6] += bf_lo(v.w); acc[7] += bf_hi(v.w);
}

// ------- prep: W convert (blocks 0..31), x convert (next xb_blocks), count_deg (rest) -------
// cnt must be zeroed (hipMemsetAsync) before this kernel runs.

__global__ void prep_kernel(const float* __restrict__ x, unsigned short* __restrict__ xb,
                            int total8, int xb_blocks,
                            const float* __restrict__ W0, const float* __restrict__ W1,
                            const float* __restrict__ W2, const float* __restrict__ W3,
                            unsigned short* __restrict__ wt,
                            const int* __restrict__ dst, int* __restrict__ cnt, int E) {
    int bx = blockIdx.x;
    int t = threadIdx.x;
    if (bx < 32) {
        // W [128k][128n] fp32 -> wt bf16 [m][n][chunk-swizzled k]: chunk c at slot c ^ (n&15)
        int tid = bx * 256 + t;            // 0..8191
        int m = tid >> 11;
        const float* W = (m == 0) ? W0 : (m == 1) ? W1 : (m == 2) ? W2 : W3;
        int r = tid & 2047;
        int n = r >> 4;
        int c = r & 15;
        float f[8];
#pragma unroll
        for (int i = 0; i < 8; ++i) f[i] = W[(size_t)(c * 8 + i) * 128 + n];
        uint4 o;
        o.x = pack2(f[0], f[1]);
        o.y = pack2(f[2], f[3]);
        o.z = pack2(f[4], f[5]);
        o.w = pack2(f[6], f[7]);
        *reinterpret_cast<uint4*>(wt + (size_t)m * 16384 + n * 128 + (c ^ (n & 15)) * 8) = o;
    } else if (bx < 32 + xb_blocks) {
        int i = (bx - 32) * 256 + t;
        if (i < total8) {
            const float4 v0 = *reinterpret_cast<const float4*>(x + (size_t)i * 8);
            const float4 v1 = *reinterpret_cast<const float4*>(x + (size_t)i * 8 + 4);
            uint4 o;
            o.x = pack2(v0.x, v0.y);
            o.y = pack2(v0.z, v0.w);
            o.z = pack2(v1.x, v1.y);
            o.w = pack2(v1.z, v1.w);
            *reinterpret_cast<uint4*>(xb + (size_t)i * 8) = o;
        }
    } else {
        int e = (bx - 32 - xb_blocks) * 256 + t;
        if (e < E) atomicAdd(&cnt[dst[e]], 1);
    }
}

// ---------------- CSR build ----------------

__global__ void scan1_kernel(const int* __restrict__ cnt, int* __restrict__ rowptr,
                             int* __restrict__ bsum, int N) {
    __shared__ int tmp[256];
    int tid = threadIdx.x;
    int i = blockIdx.x * 256 + tid;
    int v = (i < N) ? cnt[i] : 0;
    tmp[tid] = v;
    __syncthreads();
    for (int off = 1; off < 256; off <<= 1) {
        int t = (tid >= off) ? tmp[tid - off] : 0;
        __syncthreads();
        tmp[tid] += t;
        __syncthreads();
    }
    if (i < N) rowptr[i] = tmp[tid] - v;            // exclusive within block
    if (tid == 255) bsum[blockIdx.x] = tmp[255];    // block total
}

// scan2+scan3 fused: each block reduces its own bsum-prefix (<=256 ints), adds it on
__global__ void scan23_kernel(const int* __restrict__ bsum, int* __restrict__ rowptr,
                              int* __restrict__ cursor, int N, int E) {
    __shared__ int tmp[256];
    int bid = blockIdx.x;
    int t = threadIdx.x;
    tmp[t] = (t < bid) ? bsum[t] : 0;    // NB <= 256: one element per thread
    __syncthreads();
#pragma unroll
    for (int off = 128; off > 0; off >>= 1) {
        if (t < off) tmp[t] += tmp[t + off];
        __syncthreads();
    }
    int prefix = tmp[0];
    int i = bid * 256 + t;
    if (i < N) {
        int v = rowptr[i] + prefix;
        rowptr[i] = v;
        cursor[i] = v;
    }
    if (i == 0) rowptr[N] = E;
}

__global__ void fill_kernel(const int* __restrict__ src, const int* __restrict__ dst,
                            int* __restrict__ cursor, int* __restrict__ ssrc, int E) {
    int e = blockIdx.x * 256 + threadIdx.x;
    if (e < E) {
        int d = dst[e];
        int pos = atomicAdd(&cursor[d], 1);
        ssrc[pos] = src[e];
    }
}

// ---------------- mean aggregation (bf16 in, bf16 out, fp32 accum) ----------------
// one wave per node; quarter-waves process edges e ≡ q (mod 4), unrolled x2 so two
// independent ssrc-loads + two independent 256B gathers are in flight per iteration.
// NO cross-lane ops inside divergent control flow (r7 lesson: __shfl from lanes whose
// quarter-wave exited the loop reads undefined data on CDNA).

__global__ void agg_kernel(const unsigned short* __restrict__ feat, const int* __restrict__ rowptr,
                           const int* __restrict__ ssrc, unsigned short* __restrict__ out, int N) {
    int node = (blockIdx.x * blockDim.x + threadIdx.x) >> 6;
    if (node >= N) return;
    int lane = threadIdx.x & 63;
    int q = lane >> 4;
    int l15 = lane & 15;
    int beg = rowptr[node], end = rowptr[node + 1];
    int deg = end - beg;
    float acc[8] = {0.f, 0.f, 0.f, 0.f, 0.f, 0.f, 0.f, 0.f};
    int e = beg + q;
    for (; e + 4 < end; e += 8) {
        int s0 = ssrc[e];          // same addr across the quarter-wave -> broadcast
        int s1 = ssrc[e + 4];      // independent: both index loads issue together
        uint4 v0 = *reinterpret_cast<const uint4*>(feat + (size_t)s0 * D + l15 * 8);
        uint4 v1 = *reinterpret_cast<const uint4*>(feat + (size_t)s1 * D + l15 * 8);
        acc8(acc, v0);
        acc8(acc, v1);
    }
    if (e < end) {
        int s0 = ssrc[e];
        uint4 v0 = *reinterpret_cast<const uint4*>(feat + (size_t)s0 * D + l15 * 8);
        acc8(acc, v0);
    }
    // full reconvergence here; wave-uniform path below
#pragma unroll
    for (int j = 0; j < 8; ++j) {
        acc[j] += __shfl_xor(acc[j], 16);
        acc[j] += __shfl_xor(acc[j], 32);
    }
    if (lane < 16) {
        float inv = 1.0f / (float)(deg > 1 ? deg : 1);
        uint4 o;
        o.x = pack2(acc[0] * inv, acc[1] * inv);
        o.y = pack2(acc[2] * inv, acc[3] * inv);
        o.z = pack2(acc[4] * inv, acc[5] * inv);
        o.w = pack2(acc[6] * inv, acc[7] * inv);
        *reinterpret_cast<uint4*>(out + (size_t)node * D + l15 * 8) = o;
    }
}

// ---------------- MFMA dual-GEMM: out = A1*Wt[0] + A2*Wt[1] + bias [, relu] ----------------
// block: 256 thr / 4 waves; tile 128 rows x 128 cols; wave = 32 rows (M_rep=2) x 128 cols (N_rep=8).
// No A staging (each A row consumed by exactly one block). Both W passes in 64 KB LDS. ONE barrier.

template <bool RELU, bool OUT_BF16>
__global__ __launch_bounds__(256)
void gemm_mfma_kernel(const unsigned short* __restrict__ A1, const unsigned short* __restrict__ A2,
                      const unsigned short* __restrict__ Wt,   // [2][128n][128k-swz] bf16
                      const float* __restrict__ bias, void* __restrict__ outp, int N) {
    __shared__ unsigned short Wlds[2][128 * 128];   // 64 KB, swizzle baked in global layout

    const int t = threadIdx.x;
    const int w = t >> 6;
    const int lane = t & 63;
    const int l15 = lane & 15;
    const int g = lane >> 4;
    const size_t row0 = (size_t)blockIdx.x * 128;

#pragma unroll
    for (int i = 0; i < 16; ++i) {
        int d = t + 256 * i;    // short8 index 0..4095
        __builtin_amdgcn_global_load_lds((glb_u32_t*)(Wt + (size_t)d * 8),
                                         (lds_u32_t*)(&Wlds[0][0] + (size_t)d * 8), 16, 0, 0);
    }

    // preload all A fragments direct from global (rows >= N read junk; outputs dropped)
    short8 a[2][2][4];   // [pass][row-group][kiter]
#pragma unroll
    for (int p = 0; p < 2; ++p) {
        const unsigned short* __restrict__ Ap = p ? A2 : A1;
#pragma unroll
        for (int m = 0; m < 2; ++m) {
            size_t r = row0 + w * 32 + m * 16 + l15;
#pragma unroll
            for (int k = 0; k < 4; ++k)
                a[p][m][k] = *reinterpret_cast<const short8*>(Ap + r * D + (k * 4 + g) * 8);
        }
    }

    float bb[8];
#pragma unroll
    for (int j = 0; j < 8; ++j) bb[j] = bias[j * 16 + l15];

    f32x4 acc[2][8];
#pragma unroll
    for (int m = 0; m < 2; ++m)
#pragma unroll
        for (int j = 0; j < 8; ++j) acc[m][j] = (f32x4){0.f, 0.f, 0.f, 0.f};

    __syncthreads();   // drains vmcnt: W in LDS, A in regs

#pragma unroll
    for (int p = 0; p < 2; ++p)
#pragma unroll
        for (int k = 0; k < 4; ++k) {
            int c = k * 4 + g;
#pragma unroll
            for (int j = 0; j < 8; ++j) {
                short8 b = *reinterpret_cast<const short8*>(
                    &Wlds[p][(j * 16 + l15) * 128 + ((c ^ l15) * 8)]);
                acc[0][j] = __builtin_amdgcn_mfma_f32_16x16x32_bf16(a[p][0][k], b, acc[0][j], 0, 0, 0);
                acc[1][j] = __builtin_amdgcn_mfma_f32_16x16x32_bf16(a[p][1][k], b, acc[1][j], 0, 0, 0);
            }
        }

    // epilogue: C/D layout col=lane&15, row=(lane>>4)*4+reg
    unsigned short* outb = (unsigned short*)outp;
    float* outf = (float*)outp;
#pragma unroll
    for (int m = 0; m < 2; ++m) {
        size_t rbase = row0 + w * 32 + m * 16 + g * 4;
#pragma unroll
        for (int reg = 0; reg < 4; ++reg) {
            size_t row = rbase + reg;
            if (row < (size_t)N) {
#pragma unroll
                for (int j = 0; j < 8; ++j) {
                    float v = acc[m][j][reg] + bb[j];
                    if (RELU) v = v > 0.f ? v : 0.f;
                    if (OUT_BF16) outb[row * D + j * 16 + l15] = f2bf(v);
                    else          outf[row * D + j * 16 + l15] = v;
                }
            }
        }
    }
}

// ---------------- launch ----------------

extern "C" void kernel_launch(void* const* d_in, const int* in_sizes, int n_in,
                              void* d_out, int out_size, void* d_ws, size_t ws_size,
                              hipStream_t stream) {
    const float* x    = (const float*)d_in[0];
    const int*   eidx = (const int*)d_in[1];
    const float* W_l1 = (const float*)d_in[2];
    const float* W_r1 = (const float*)d_in[3];
    const float* b1   = (const float*)d_in[4];
    const float* W_l2 = (const float*)d_in[5];
    const float* W_r2 = (const float*)d_in[6];
    const float* b2   = (const float*)d_in[7];
    float* out = (float*)d_out;

    const int N = in_sizes[0] / D;
    const int E = in_sizes[1] / 2;
    const int N_pad = (N + 127) & ~127;
    const int* src = eidx;
    const int* dst = eidx + E;

    char* ws = (char*)d_ws;
    size_t off = 0;
    auto alloc = [&](size_t bytes) {
        char* p = ws + off;
        off += (bytes + 511) & ~(size_t)511;
        return p;
    };
    int*            cnt    = (int*)alloc((size_t)N * 4);
    int*            rowptr = (int*)alloc((size_t)(N + 1) * 4);
    int*            cursor = (int*)alloc((size_t)N * 4);
    int*            bsum   = (int*)alloc(1024);
    int*            ssrc   = (int*)alloc((size_t)E * 4);
    unsigned short* xb     = (unsigned short*)alloc((size_t)N_pad * D * 2);
    unsigned short* hb     = (unsigned short*)alloc((size_t)N_pad * D * 2);
    unsigned short* aggb   = (unsigned short*)alloc((size_t)N_pad * D * 2);
    unsigned short* wt     = (unsigned short*)alloc((size_t)4 * 128 * 128 * 2);

    const int total8    = N * D / 8;
    const int xb_blocks = (total8 + 255) / 256;
    const int NB_edges  = (E + 255) / 256;
    const int NB_prep   = 32 + xb_blocks + NB_edges;
    const int NB_nodes  = (N + 255) / 256;   // 196 <= 256: scan23 one-elem-per-thread OK
    const int NB_agg    = (N + 3) / 4;
    const int NB_gemm   = N_pad / 128;

    // CSR + conversions
    hipMemsetAsync(cnt, 0, (size_t)N * 4, stream);
    prep_kernel<<<NB_prep, 256, 0, stream>>>(x, xb, total8, xb_blocks,
                                             W_l1, W_r1, W_l2, W_r2, wt, dst, cnt, E);
    scan1_kernel<<<NB_nodes, 256, 0, stream>>>(cnt, rowptr, bsum, N);
    scan23_kernel<<<NB_nodes, 256, 0, stream>>>(bsum, rowptr, cursor, N, E);
    fill_kernel<<<NB_edges, 256, 0, stream>>>(src, dst, cursor, ssrc, E);

    // layer 1
    agg_kernel<<<NB_agg, 256, 0, stream>>>(xb, rowptr, ssrc, aggb, N);
    gemm_mfma_kernel<true, true><<<NB_gemm, 256, 0, stream>>>(aggb, xb, wt, b1, hb, N);

    // layer 2
    agg_kernel<<<NB_agg, 256, 0, stream>>>(hb, rowptr, ssrc, aggb, N);
    gemm_mfma_kernel<false, false><<<NB_gemm, 256, 0, stream>>>(aggb, hb, wt + 2 * 16384, b2, out, N);
}

// Round 9
// 108.329 us; speedup vs baseline: 1.8436x; 1.3735x over previous
//
#include <hip/hip_runtime.h>

#define D 128
#define CAP 4096   // bucket capacity (mean 3061, sigma ~55 at E=600K -> +18 sigma)

typedef __attribute__((ext_vector_type(8))) short short8;
typedef __attribute__((ext_vector_type(4))) float f32x4;

typedef __attribute__((address_space(3))) unsigned int lds_u32_t;
typedef const __attribute__((address_space(1))) unsigned int glb_u32_t;

static __device__ __forceinline__ unsigned short f2bf(float f) {
    unsigned int u = __float_as_uint(f);
    unsigned int r = (u + 0x7fffu + ((u >> 16) & 1u)) >> 16;
    return (unsigned short)r;
}
static __device__ __forceinline__ float bf_lo(unsigned int u) {
    return __uint_as_float(u << 16);
}
static __device__ __forceinline__ float bf_hi(unsigned int u) {
    return __uint_as_float(u & 0xffff0000u);
}
static __device__ __forceinline__ unsigned int pack2(float lo, float hi) {
    return (unsigned int)f2bf(lo) | ((unsigned int)f2bf(hi) << 16);
}
static __device__ __forceinline__ void acc8(float* acc, uint4 v) {
    acc[0] += bf_lo(v.x); acc[1] += bf_hi(v.x);
    acc[2] += bf_lo(v.y); acc[3] += bf_hi(v.y);
    acc[4] += bf_lo(v.z); acc[5] += bf_hi(v.z);
    acc[6] += bf_lo(v.w); acc[7] += bf_hi(v.w);
}

// ------- prep: W convert (blocks 0..31, block 0 also zeroes bucket_cnt), x convert (rest) -------

__global__ void prep_kernel(const float* __restrict__ x, unsigned short* __restrict__ xb,
                            int total8,
                            const float* __restrict__ W0, const float* __restrict__ W1,
                            const float* __restrict__ W2, const float* __restrict__ W3,
                            unsigned short* __restrict__ wt,
                            int* __restrict__ bucket_cnt) {
    int bx = blockIdx.x;
    int t = threadIdx.x;
    if (bx == 0) bucket_cnt[t] = 0;     // 256 ints
    if (bx < 32) {
        // W [128k][128n] fp32 -> wt bf16 [m][n][chunk-swizzled k]: chunk c at slot c ^ (n&15)
        int tid = bx * 256 + t;            // 0..8191
        int m = tid >> 11;
        const float* W = (m == 0) ? W0 : (m == 1) ? W1 : (m == 2) ? W2 : W3;
        int r = tid & 2047;
        int n = r >> 4;
        int c = r & 15;
        float f[8];
#pragma unroll
        for (int i = 0; i < 8; ++i) f[i] = W[(size_t)(c * 8 + i) * 128 + n];
        uint4 o;
        o.x = pack2(f[0], f[1]);
        o.y = pack2(f[2], f[3]);
        o.z = pack2(f[4], f[5]);
        o.w = pack2(f[6], f[7]);
        *reinterpret_cast<uint4*>(wt + (size_t)m * 16384 + n * 128 + (c ^ (n & 15)) * 8) = o;
    } else {
        int i = (bx - 32) * 256 + t;
        if (i < total8) {
            const float4 v0 = *reinterpret_cast<const float4*>(x + (size_t)i * 8);
            const float4 v1 = *reinterpret_cast<const float4*>(x + (size_t)i * 8 + 4);
            uint4 o;
            o.x = pack2(v0.x, v0.y);
            o.y = pack2(v0.z, v0.w);
            o.z = pack2(v1.x, v1.y);
            o.w = pack2(v1.z, v1.w);
            *reinterpret_cast<uint4*>(xb + (size_t)i * 8) = o;
        }
    }
}

// ---------------- bucketed CSR build ----------------
// Pass A: bin edges by dst>>8. Per block: LDS histogram -> one global reservation per
// bucket -> scatter packed (dstlocal<<24 | src) into bucket regions.

__global__ void bucketA_kernel(const int* __restrict__ src, const int* __restrict__ dst,
                               int* __restrict__ bucket_cnt, unsigned int* __restrict__ bucket_buf,
                               int E) {
    __shared__ int hist[256];
    __shared__ int cur[256];
    int t = threadIdx.x;
    hist[t] = 0;
    __syncthreads();
    int base = blockIdx.x * 4096;
#pragma unroll
    for (int i = 0; i < 16; ++i) {
        int e = base + t + i * 256;
        if (e < E) atomicAdd(&hist[dst[e] >> 8], 1);
    }
    __syncthreads();
    if (hist[t] > 0) cur[t] = atomicAdd(&bucket_cnt[t], hist[t]);
    __syncthreads();
#pragma unroll
    for (int i = 0; i < 16; ++i) {
        int e = base + t + i * 256;
        if (e < E) {
            int d = dst[e];
            int s = src[e];
            int b = d >> 8;
            int pos = atomicAdd(&cur[b], 1);
            bucket_buf[(size_t)b * CAP + pos] = ((unsigned)(d & 255) << 24) | (unsigned)s;
        }
    }
}

// Pass B: one block per bucket. Node histogram in LDS -> scan -> rowptr (coalesced) +
// scatter src into the bucket's CSR segment (~12 KB window, line-local).

__global__ void bucketB_kernel(const int* __restrict__ bucket_cnt,
                               const unsigned int* __restrict__ bucket_buf,
                               int* __restrict__ rowptr, int* __restrict__ ssrc,
                               int N, int E, int nbkt) {
    __shared__ int pref[256];
    __shared__ int lsc[256];
    int b = blockIdx.x;
    int t = threadIdx.x;
    // inclusive scan of bucket sizes (every block does the same tiny scan)
    pref[t] = (t < nbkt) ? bucket_cnt[t] : 0;
    __syncthreads();
    for (int off = 1; off < 256; off <<= 1) {
        int u = (t >= off) ? pref[t - off] : 0;
        __syncthreads();
        pref[t] += u;
        __syncthreads();
    }
    int cnt_b = bucket_cnt[b];
    int base_b = pref[b] - cnt_b;      // exclusive global base of this bucket
    // local node histogram
    lsc[t] = 0;
    __syncthreads();
    for (int i = t; i < cnt_b; i += 256)
        atomicAdd(&lsc[bucket_buf[(size_t)b * CAP + i] >> 24], 1);
    __syncthreads();
    int c = lsc[t];
    __syncthreads();
    // inclusive scan of node counts
    for (int off = 1; off < 256; off <<= 1) {
        int u = (t >= off) ? lsc[t - off] : 0;
        __syncthreads();
        lsc[t] += u;
        __syncthreads();
    }
    int mybase = base_b + lsc[t] - c;   // exclusive global start for node b*256+t
    int node = b * 256 + t;
    if (node < N) rowptr[node] = mybase;
    if (b == nbkt - 1 && t == 0) rowptr[N] = E;
    __syncthreads();
    lsc[t] = mybase;                    // reuse as global cursor
    __syncthreads();
    for (int i = t; i < cnt_b; i += 256) {
        unsigned v = bucket_buf[(size_t)b * CAP + i];
        int pos = atomicAdd(&lsc[v >> 24], 1);
        ssrc[pos] = (int)(v & 0xFFFFFFu);
    }
}

// ---------------- mean aggregation (bf16 in, bf16 out, fp32 accum) ----------------
// one wave per node; quarter-waves process edges e ≡ q (mod 4), unrolled x2 so two
// independent ssrc-loads + two independent 256B gathers are in flight per iteration.
// NO cross-lane ops inside divergent control flow (r7 lesson).

__global__ void agg_kernel(const unsigned short* __restrict__ feat, const int* __restrict__ rowptr,
                           const int* __restrict__ ssrc, unsigned short* __restrict__ out, int N) {
    int node = (blockIdx.x * blockDim.x + threadIdx.x) >> 6;
    if (node >= N) return;
    int lane = threadIdx.x & 63;
    int q = lane >> 4;
    int l15 = lane & 15;
    int beg = rowptr[node], end = rowptr[node + 1];
    int deg = end - beg;
    float acc[8] = {0.f, 0.f, 0.f, 0.f, 0.f, 0.f, 0.f, 0.f};
    int e = beg + q;
    for (; e + 4 < end; e += 8) {
        int s0 = ssrc[e];          // same addr across quarter-wave -> broadcast
        int s1 = ssrc[e + 4];
        uint4 v0 = *reinterpret_cast<const uint4*>(feat + (size_t)s0 * D + l15 * 8);
        uint4 v1 = *reinterpret_cast<const uint4*>(feat + (size_t)s1 * D + l15 * 8);
        acc8(acc, v0);
        acc8(acc, v1);
    }
    if (e < end) {
        int s0 = ssrc[e];
        uint4 v0 = *reinterpret_cast<const uint4*>(feat + (size_t)s0 * D + l15 * 8);
        acc8(acc, v0);
    }
#pragma unroll
    for (int j = 0; j < 8; ++j) {
        acc[j] += __shfl_xor(acc[j], 16);
        acc[j] += __shfl_xor(acc[j], 32);
    }
    if (lane < 16) {
        float inv = 1.0f / (float)(deg > 1 ? deg : 1);
        uint4 o;
        o.x = pack2(acc[0] * inv, acc[1] * inv);
        o.y = pack2(acc[2] * inv, acc[3] * inv);
        o.z = pack2(acc[4] * inv, acc[5] * inv);
        o.w = pack2(acc[6] * inv, acc[7] * inv);
        *reinterpret_cast<uint4*>(out + (size_t)node * D + l15 * 8) = o;
    }
}

// ---------------- MFMA dual-GEMM: out = A1*Wt[0] + A2*Wt[1] + bias [, relu] ----------------
// block: 256 thr / 4 waves; tile 128 rows x 128 cols; wave = 32 rows (M_rep=2) x 128 cols.
// No A staging (each A row consumed by exactly one block). Both W passes in 64 KB LDS. ONE barrier.

template <bool RELU, bool OUT_BF16>
__global__ __launch_bounds__(256)
void gemm_mfma_kernel(const unsigned short* __restrict__ A1, const unsigned short* __restrict__ A2,
                      const unsigned short* __restrict__ Wt,   // [2][128n][128k-swz] bf16
                      const float* __restrict__ bias, void* __restrict__ outp, int N) {
    __shared__ unsigned short Wlds[2][128 * 128];   // 64 KB, swizzle baked in global layout

    const int t = threadIdx.x;
    const int w = t >> 6;
    const int lane = t & 63;
    const int l15 = lane & 15;
    const int g = lane >> 4;
    const size_t row0 = (size_t)blockIdx.x * 128;

#pragma unroll
    for (int i = 0; i < 16; ++i) {
        int d = t + 256 * i;    // short8 index 0..4095
        __builtin_amdgcn_global_load_lds((glb_u32_t*)(Wt + (size_t)d * 8),
                                         (lds_u32_t*)(&Wlds[0][0] + (size_t)d * 8), 16, 0, 0);
    }

    // preload all A fragments direct from global (rows >= N read junk; outputs dropped)
    short8 a[2][2][4];   // [pass][row-group][kiter]
#pragma unroll
    for (int p = 0; p < 2; ++p) {
        const unsigned short* __restrict__ Ap = p ? A2 : A1;
#pragma unroll
        for (int m = 0; m < 2; ++m) {
            size_t r = row0 + w * 32 + m * 16 + l15;
#pragma unroll
            for (int k = 0; k < 4; ++k)
                a[p][m][k] = *reinterpret_cast<const short8*>(Ap + r * D + (k * 4 + g) * 8);
        }
    }

    float bb[8];
#pragma unroll
    for (int j = 0; j < 8; ++j) bb[j] = bias[j * 16 + l15];

    f32x4 acc[2][8];
#pragma unroll
    for (int m = 0; m < 2; ++m)
#pragma unroll
        for (int j = 0; j < 8; ++j) acc[m][j] = (f32x4){0.f, 0.f, 0.f, 0.f};

    __syncthreads();   // drains vmcnt: W in LDS, A in regs

#pragma unroll
    for (int p = 0; p < 2; ++p)
#pragma unroll
        for (int k = 0; k < 4; ++k) {
            int c = k * 4 + g;
#pragma unroll
            for (int j = 0; j < 8; ++j) {
                short8 b = *reinterpret_cast<const short8*>(
                    &Wlds[p][(j * 16 + l15) * 128 + ((c ^ l15) * 8)]);
                acc[0][j] = __builtin_amdgcn_mfma_f32_16x16x32_bf16(a[p][0][k], b, acc[0][j], 0, 0, 0);
                acc[1][j] = __builtin_amdgcn_mfma_f32_16x16x32_bf16(a[p][1][k], b, acc[1][j], 0, 0, 0);
            }
        }

    // epilogue: C/D layout col=lane&15, row=(lane>>4)*4+reg
    unsigned short* outb = (unsigned short*)outp;
    float* outf = (float*)outp;
#pragma unroll
    for (int m = 0; m < 2; ++m) {
        size_t rbase = row0 + w * 32 + m * 16 + g * 4;
#pragma unroll
        for (int reg = 0; reg < 4; ++reg) {
            size_t row = rbase + reg;
            if (row < (size_t)N) {
#pragma unroll
                for (int j = 0; j < 8; ++j) {
                    float v = acc[m][j][reg] + bb[j];
                    if (RELU) v = v > 0.f ? v : 0.f;
                    if (OUT_BF16) outb[row * D + j * 16 + l15] = f2bf(v);
                    else          outf[row * D + j * 16 + l15] = v;
                }
            }
        }
    }
}

// ---------------- launch ----------------

extern "C" void kernel_launch(void* const* d_in, const int* in_sizes, int n_in,
                              void* d_out, int out_size, void* d_ws, size_t ws_size,
                              hipStream_t stream) {
    const float* x    = (const float*)d_in[0];
    const int*   eidx = (const int*)d_in[1];
    const float* W_l1 = (const float*)d_in[2];
    const float* W_r1 = (const float*)d_in[3];
    const float* b1   = (const float*)d_in[4];
    const float* W_l2 = (const float*)d_in[5];
    const float* W_r2 = (const float*)d_in[6];
    const float* b2   = (const float*)d_in[7];
    float* out = (float*)d_out;

    const int N = in_sizes[0] / D;
    const int E = in_sizes[1] / 2;
    const int N_pad = (N + 127) & ~127;
    const int nbkt = (N + 255) >> 8;    // 196 for N=50000 (must be <= 256)
    const int* src = eidx;
    const int* dst = eidx + E;

    char* ws = (char*)d_ws;
    size_t off = 0;
    auto alloc = [&](size_t bytes) {
        char* p = ws + off;
        off += (bytes + 511) & ~(size_t)511;
        return p;
    };
    int*            rowptr     = (int*)alloc((size_t)(N + 1) * 4);
    int*            bucket_cnt = (int*)alloc(1024);
    unsigned int*   bucket_buf = (unsigned int*)alloc((size_t)nbkt * CAP * 4);
    int*            ssrc       = (int*)alloc((size_t)E * 4);
    unsigned short* xb         = (unsigned short*)alloc((size_t)N_pad * D * 2);
    unsigned short* hb         = (unsigned short*)alloc((size_t)N_pad * D * 2);
    unsigned short* aggb       = (unsigned short*)alloc((size_t)N_pad * D * 2);
    unsigned short* wt         = (unsigned short*)alloc((size_t)4 * 128 * 128 * 2);

    const int total8    = N * D / 8;
    const int xb_blocks = (total8 + 255) / 256;
    const int NB_prep   = 32 + xb_blocks;
    const int NB_bktA   = (E + 4095) / 4096;
    const int NB_agg    = (N + 3) / 4;
    const int NB_gemm   = N_pad / 128;

    // conversions + bucketed CSR build
    prep_kernel<<<NB_prep, 256, 0, stream>>>(x, xb, total8, W_l1, W_r1, W_l2, W_r2, wt, bucket_cnt);
    bucketA_kernel<<<NB_bktA, 256, 0, stream>>>(src, dst, bucket_cnt, bucket_buf, E);
    bucketB_kernel<<<nbkt, 256, 0, stream>>>(bucket_cnt, bucket_buf, rowptr, ssrc, N, E, nbkt);

    // layer 1
    agg_kernel<<<NB_agg, 256, 0, stream>>>(xb, rowptr, ssrc, aggb, N);
    gemm_mfma_kernel<true, true><<<NB_gemm, 256, 0, stream>>>(aggb, xb, wt, b1, hb, N);

    // layer 2
    agg_kernel<<<NB_agg, 256, 0, stream>>>(hb, rowptr, ssrc, aggb, N);
    gemm_mfma_kernel<false, false><<<NB_gemm, 256, 0, stream>>>(aggb, hb, wt + 2 * 16384, b2, out, N);
}

// Round 10
// 102.017 us; speedup vs baseline: 1.9577x; 1.0619x over previous
//
#include <hip/hip_runtime.h>

#define D 128
#define CAP 4096   // bucket capacity (mean 3061, sigma ~55 at E=600K -> +18 sigma)

typedef __attribute__((ext_vector_type(8))) short short8;
typedef __attribute__((ext_vector_type(4))) float f32x4;

typedef __attribute__((address_space(3))) unsigned int lds_u32_t;
typedef const __attribute__((address_space(1))) unsigned int glb_u32_t;

static __device__ __forceinline__ unsigned short f2bf(float f) {
    unsigned int u = __float_as_uint(f);
    unsigned int r = (u + 0x7fffu + ((u >> 16) & 1u)) >> 16;
    return (unsigned short)r;
}
static __device__ __forceinline__ float bf_lo(unsigned int u) {
    return __uint_as_float(u << 16);
}
static __device__ __forceinline__ float bf_hi(unsigned int u) {
    return __uint_as_float(u & 0xffff0000u);
}
static __device__ __forceinline__ unsigned int pack2(float lo, float hi) {
    return (unsigned int)f2bf(lo) | ((unsigned int)f2bf(hi) << 16);
}
// weighted accumulate: w=0 nullifies dummy gathers (branch-free predication)
static __device__ __forceinline__ void acc8w(float* acc, uint4 v, float w) {
    acc[0] = fmaf(bf_lo(v.x), w, acc[0]); acc[1] = fmaf(bf_hi(v.x), w, acc[1]);
    acc[2] = fmaf(bf_lo(v.y), w, acc[2]); acc[3] = fmaf(bf_hi(v.y), w, acc[3]);
    acc[4] = fmaf(bf_lo(v.z), w, acc[4]); acc[5] = fmaf(bf_hi(v.z), w, acc[5]);
    acc[6] = fmaf(bf_lo(v.w), w, acc[6]); acc[7] = fmaf(bf_hi(v.w), w, acc[7]);
}

// ------- prep: W convert (blocks 0..31, block 0 also zeroes bucket_cnt), x convert (rest) -------

__global__ void prep_kernel(const float* __restrict__ x, unsigned short* __restrict__ xb,
                            int total8,
                            const float* __restrict__ W0, const float* __restrict__ W1,
                            const float* __restrict__ W2, const float* __restrict__ W3,
                            unsigned short* __restrict__ wt,
                            int* __restrict__ bucket_cnt) {
    int bx = blockIdx.x;
    int t = threadIdx.x;
    if (bx == 0) bucket_cnt[t] = 0;     // 256 ints
    if (bx < 32) {
        // W [128k][128n] fp32 -> wt bf16 [m][n][chunk-swizzled k]: chunk c at slot c ^ (n&15)
        int tid = bx * 256 + t;            // 0..8191
        int m = tid >> 11;
        const float* W = (m == 0) ? W0 : (m == 1) ? W1 : (m == 2) ? W2 : W3;
        int r = tid & 2047;
        int n = r >> 4;
        int c = r & 15;
        float f[8];
#pragma unroll
        for (int i = 0; i < 8; ++i) f[i] = W[(size_t)(c * 8 + i) * 128 + n];
        uint4 o;
        o.x = pack2(f[0], f[1]);
        o.y = pack2(f[2], f[3]);
        o.z = pack2(f[4], f[5]);
        o.w = pack2(f[6], f[7]);
        *reinterpret_cast<uint4*>(wt + (size_t)m * 16384 + n * 128 + (c ^ (n & 15)) * 8) = o;
    } else {
        int i = (bx - 32) * 256 + t;
        if (i < total8) {
            const float4 v0 = *reinterpret_cast<const float4*>(x + (size_t)i * 8);
            const float4 v1 = *reinterpret_cast<const float4*>(x + (size_t)i * 8 + 4);
            uint4 o;
            o.x = pack2(v0.x, v0.y);
            o.y = pack2(v0.z, v0.w);
            o.z = pack2(v1.x, v1.y);
            o.w = pack2(v1.z, v1.w);
            *reinterpret_cast<uint4*>(xb + (size_t)i * 8) = o;
        }
    }
}

// ---------------- bucketed CSR build ----------------
// Pass A: bin edges by dst>>8. Per block: LDS histogram -> one global reservation per
// bucket -> scatter packed (dstlocal<<24 | src) into bucket regions.

__global__ void bucketA_kernel(const int* __restrict__ src, const int* __restrict__ dst,
                               int* __restrict__ bucket_cnt, unsigned int* __restrict__ bucket_buf,
                               int E) {
    __shared__ int hist[256];
    __shared__ int cur[256];
    int t = threadIdx.x;
    hist[t] = 0;
    __syncthreads();
    int base = blockIdx.x * 4096;
#pragma unroll
    for (int i = 0; i < 16; ++i) {
        int e = base + t + i * 256;
        if (e < E) atomicAdd(&hist[dst[e] >> 8], 1);
    }
    __syncthreads();
    if (hist[t] > 0) cur[t] = atomicAdd(&bucket_cnt[t], hist[t]);
    __syncthreads();
#pragma unroll
    for (int i = 0; i < 16; ++i) {
        int e = base + t + i * 256;
        if (e < E) {
            int d = dst[e];
            int s = src[e];
            int b = d >> 8;
            int pos = atomicAdd(&cur[b], 1);
            bucket_buf[(size_t)b * CAP + pos] = ((unsigned)(d & 255) << 24) | (unsigned)s;
        }
    }
}

// Pass B: one block per bucket. Node histogram in LDS -> scan -> rowptr (coalesced) +
// scatter src into the bucket's CSR segment (~12 KB window, line-local).

__global__ void bucketB_kernel(const int* __restrict__ bucket_cnt,
                               const unsigned int* __restrict__ bucket_buf,
                               int* __restrict__ rowptr, int* __restrict__ ssrc,
                               int N, int E, int nbkt) {
    __shared__ int pref[256];
    __shared__ int lsc[256];
    int b = blockIdx.x;
    int t = threadIdx.x;
    // inclusive scan of bucket sizes (every block does the same tiny scan)
    pref[t] = (t < nbkt) ? bucket_cnt[t] : 0;
    __syncthreads();
    for (int off = 1; off < 256; off <<= 1) {
        int u = (t >= off) ? pref[t - off] : 0;
        __syncthreads();
        pref[t] += u;
        __syncthreads();
    }
    int cnt_b = bucket_cnt[b];
    int base_b = pref[b] - cnt_b;      // exclusive global base of this bucket
    // local node histogram
    lsc[t] = 0;
    __syncthreads();
    for (int i = t; i < cnt_b; i += 256)
        atomicAdd(&lsc[bucket_buf[(size_t)b * CAP + i] >> 24], 1);
    __syncthreads();
    int c = lsc[t];
    __syncthreads();
    // inclusive scan of node counts
    for (int off = 1; off < 256; off <<= 1) {
        int u = (t >= off) ? lsc[t - off] : 0;
        __syncthreads();
        lsc[t] += u;
        __syncthreads();
    }
    int mybase = base_b + lsc[t] - c;   // exclusive global start for node b*256+t
    int node = b * 256 + t;
    if (node < N) rowptr[node] = mybase;
    if (b == nbkt - 1 && t == 0) rowptr[N] = E;
    __syncthreads();
    lsc[t] = mybase;                    // reuse as global cursor
    __syncthreads();
    for (int i = t; i < cnt_b; i += 256) {
        unsigned v = bucket_buf[(size_t)b * CAP + i];
        int pos = atomicAdd(&lsc[v >> 24], 1);
        ssrc[pos] = (int)(v & 0xFFFFFFu);
    }
}

// ---------------- mean aggregation (bf16 in, bf16 out, fp32 accum) ----------------
// one wave per node. ONE coalesced wave-wide index load, then windows of 16 edges:
// wave-uniform trip count (all 64 lanes active at every __shfl — r7 hazard structurally
// gone), quarter-wave q gathers edges j+q, j+4+q, j+8+q, j+12+q as 4 independent
// in-flight 256B gathers; invalid slots gather row 0 (L1 broadcast) with fma weight 0.

__global__ void agg_kernel(const unsigned short* __restrict__ feat, const int* __restrict__ rowptr,
                           const int* __restrict__ ssrc, unsigned short* __restrict__ out, int N) {
    int node = (blockIdx.x * blockDim.x + threadIdx.x) >> 6;
    if (node >= N) return;               // wave-uniform
    int lane = threadIdx.x & 63;
    int q = lane >> 4;
    int l15 = lane & 15;
    int beg = rowptr[node], end = rowptr[node + 1];
    int deg = end - beg;
    float acc[8] = {0.f, 0.f, 0.f, 0.f, 0.f, 0.f, 0.f, 0.f};
    for (int base = 0; base < deg; base += 64) {
        int m = deg - base;
        if (m > 64) m = 64;              // wave-uniform window size
        int sidx = 0;
        if (lane < m) sidx = ssrc[beg + base + lane];   // one coalesced load
        for (int j = 0; j < m; j += 16) {               // uniform bound: shfl always full-wave
            int e0 = j + q, e1 = j + 4 + q, e2 = j + 8 + q, e3 = j + 12 + q;
            int s0 = __shfl(sidx, e0);
            int s1 = __shfl(sidx, e1);
            int s2 = __shfl(sidx, e2);
            int s3 = __shfl(sidx, e3);
            float w0 = (e0 < m) ? 1.f : 0.f;
            float w1 = (e1 < m) ? 1.f : 0.f;
            float w2 = (e2 < m) ? 1.f : 0.f;
            float w3 = (e3 < m) ? 1.f : 0.f;
            if (e0 >= m) s0 = 0;         // safe row; weight 0 nullifies
            if (e1 >= m) s1 = 0;
            if (e2 >= m) s2 = 0;
            if (e3 >= m) s3 = 0;
            uint4 v0 = *reinterpret_cast<const uint4*>(feat + (size_t)s0 * D + l15 * 8);
            uint4 v1 = *reinterpret_cast<const uint4*>(feat + (size_t)s1 * D + l15 * 8);
            uint4 v2 = *reinterpret_cast<const uint4*>(feat + (size_t)s2 * D + l15 * 8);
            uint4 v3 = *reinterpret_cast<const uint4*>(feat + (size_t)s3 * D + l15 * 8);
            acc8w(acc, v0, w0);
            acc8w(acc, v1, w1);
            acc8w(acc, v2, w2);
            acc8w(acc, v3, w3);
        }
    }
#pragma unroll
    for (int j = 0; j < 8; ++j) {
        acc[j] += __shfl_xor(acc[j], 16);
        acc[j] += __shfl_xor(acc[j], 32);
    }
    if (lane < 16) {
        float inv = 1.0f / (float)(deg > 1 ? deg : 1);
        uint4 o;
        o.x = pack2(acc[0] * inv, acc[1] * inv);
        o.y = pack2(acc[2] * inv, acc[3] * inv);
        o.z = pack2(acc[4] * inv, acc[5] * inv);
        o.w = pack2(acc[6] * inv, acc[7] * inv);
        *reinterpret_cast<uint4*>(out + (size_t)node * D + l15 * 8) = o;
    }
}

// ---------------- MFMA dual-GEMM: out = A1*Wt[0] + A2*Wt[1] + bias [, relu] ----------------
// block: 256 thr / 4 waves; tile 128 rows x 128 cols; wave = 32 rows (M_rep=2) x 128 cols.
// No A staging (each A row consumed by exactly one block). Both W passes in 64 KB LDS. ONE barrier.

template <bool RELU, bool OUT_BF16>
__global__ __launch_bounds__(256)
void gemm_mfma_kernel(const unsigned short* __restrict__ A1, const unsigned short* __restrict__ A2,
                      const unsigned short* __restrict__ Wt,   // [2][128n][128k-swz] bf16
                      const float* __restrict__ bias, void* __restrict__ outp, int N) {
    __shared__ unsigned short Wlds[2][128 * 128];   // 64 KB, swizzle baked in global layout

    const int t = threadIdx.x;
    const int w = t >> 6;
    const int lane = t & 63;
    const int l15 = lane & 15;
    const int g = lane >> 4;
    const size_t row0 = (size_t)blockIdx.x * 128;

#pragma unroll
    for (int i = 0; i < 16; ++i) {
        int d = t + 256 * i;    // short8 index 0..4095
        __builtin_amdgcn_global_load_lds((glb_u32_t*)(Wt + (size_t)d * 8),
                                         (lds_u32_t*)(&Wlds[0][0] + (size_t)d * 8), 16, 0, 0);
    }

    // preload all A fragments direct from global (rows >= N read junk; outputs dropped)
    short8 a[2][2][4];   // [pass][row-group][kiter]
#pragma unroll
    for (int p = 0; p < 2; ++p) {
        const unsigned short* __restrict__ Ap = p ? A2 : A1;
#pragma unroll
        for (int m = 0; m < 2; ++m) {
            size_t r = row0 + w * 32 + m * 16 + l15;
#pragma unroll
            for (int k = 0; k < 4; ++k)
                a[p][m][k] = *reinterpret_cast<const short8*>(Ap + r * D + (k * 4 + g) * 8);
        }
    }

    float bb[8];
#pragma unroll
    for (int j = 0; j < 8; ++j) bb[j] = bias[j * 16 + l15];

    f32x4 acc[2][8];
#pragma unroll
    for (int m = 0; m < 2; ++m)
#pragma unroll
        for (int j = 0; j < 8; ++j) acc[m][j] = (f32x4){0.f, 0.f, 0.f, 0.f};

    __syncthreads();   // drains vmcnt: W in LDS, A in regs

#pragma unroll
    for (int p = 0; p < 2; ++p)
#pragma unroll
        for (int k = 0; k < 4; ++k) {
            int c = k * 4 + g;
#pragma unroll
            for (int j = 0; j < 8; ++j) {
                short8 b = *reinterpret_cast<const short8*>(
                    &Wlds[p][(j * 16 + l15) * 128 + ((c ^ l15) * 8)]);
                acc[0][j] = __builtin_amdgcn_mfma_f32_16x16x32_bf16(a[p][0][k], b, acc[0][j], 0, 0, 0);
                acc[1][j] = __builtin_amdgcn_mfma_f32_16x16x32_bf16(a[p][1][k], b, acc[1][j], 0, 0, 0);
            }
        }

    // epilogue: C/D layout col=lane&15, row=(lane>>4)*4+reg
    unsigned short* outb = (unsigned short*)outp;
    float* outf = (float*)outp;
#pragma unroll
    for (int m = 0; m < 2; ++m) {
        size_t rbase = row0 + w * 32 + m * 16 + g * 4;
#pragma unroll
        for (int reg = 0; reg < 4; ++reg) {
            size_t row = rbase + reg;
            if (row < (size_t)N) {
#pragma unroll
                for (int j = 0; j < 8; ++j) {
                    float v = acc[m][j][reg] + bb[j];
                    if (RELU) v = v > 0.f ? v : 0.f;
                    if (OUT_BF16) outb[row * D + j * 16 + l15] = f2bf(v);
                    else          outf[row * D + j * 16 + l15] = v;
                }
            }
        }
    }
}

// ---------------- launch ----------------

extern "C" void kernel_launch(void* const* d_in, const int* in_sizes, int n_in,
                              void* d_out, int out_size, void* d_ws, size_t ws_size,
                              hipStream_t stream) {
    const float* x    = (const float*)d_in[0];
    const int*   eidx = (const int*)d_in[1];
    const float* W_l1 = (const float*)d_in[2];
    const float* W_r1 = (const float*)d_in[3];
    const float* b1   = (const float*)d_in[4];
    const float* W_l2 = (const float*)d_in[5];
    const float* W_r2 = (const float*)d_in[6];
    const float* b2   = (const float*)d_in[7];
    float* out = (float*)d_out;

    const int N = in_sizes[0] / D;
    const int E = in_sizes[1] / 2;
    const int N_pad = (N + 127) & ~127;
    const int nbkt = (N + 255) >> 8;    // 196 for N=50000 (must be <= 256)
    const int* src = eidx;
    const int* dst = eidx + E;

    char* ws = (char*)d_ws;
    size_t off = 0;
    auto alloc = [&](size_t bytes) {
        char* p = ws + off;
        off += (bytes + 511) & ~(size_t)511;
        return p;
    };
    int*            rowptr     = (int*)alloc((size_t)(N + 1) * 4);
    int*            bucket_cnt = (int*)alloc(1024);
    unsigned int*   bucket_buf = (unsigned int*)alloc((size_t)nbkt * CAP * 4);
    int*            ssrc       = (int*)alloc((size_t)E * 4);
    unsigned short* xb         = (unsigned short*)alloc((size_t)N_pad * D * 2);
    unsigned short* hb         = (unsigned short*)alloc((size_t)N_pad * D * 2);
    unsigned short* aggb       = (unsigned short*)alloc((size_t)N_pad * D * 2);
    unsigned short* wt         = (unsigned short*)alloc((size_t)4 * 128 * 128 * 2);

    const int total8    = N * D / 8;
    const int xb_blocks = (total8 + 255) / 256;
    const int NB_prep   = 32 + xb_blocks;
    const int NB_bktA   = (E + 4095) / 4096;
    const int NB_agg    = (N + 3) / 4;
    const int NB_gemm   = N_pad / 128;

    // conversions + bucketed CSR build
    prep_kernel<<<NB_prep, 256, 0, stream>>>(x, xb, total8, W_l1, W_r1, W_l2, W_r2, wt, bucket_cnt);
    bucketA_kernel<<<NB_bktA, 256, 0, stream>>>(src, dst, bucket_cnt, bucket_buf, E);
    bucketB_kernel<<<nbkt, 256, 0, stream>>>(bucket_cnt, bucket_buf, rowptr, ssrc, N, E, nbkt);

    // layer 1
    agg_kernel<<<NB_agg, 256, 0, stream>>>(xb, rowptr, ssrc, aggb, N);
    gemm_mfma_kernel<true, true><<<NB_gemm, 256, 0, stream>>>(aggb, xb, wt, b1, hb, N);

    // layer 2
    agg_kernel<<<NB_agg, 256, 0, stream>>>(hb, rowptr, ssrc, aggb, N);
    gemm_mfma_kernel<false, false><<<NB_gemm, 256, 0, stream>>>(aggb, hb, wt + 2 * 16384, b2, out, N);
}